// Round 4
// baseline (756.607 us; speedup 1.0000x reference)
//
#include <hip/hip_runtime.h>

#define N_NODES 100000
#define N_EDGES 3200000
#define IN_DIM 32
#define HID 64
#define BSHIFT 6
#define BNODES 64                              // nodes per bucket
#define NB ((N_NODES + BNODES - 1) / BNODES)   // 1563 buckets

typedef unsigned short bfraw;

__device__ __forceinline__ bfraw f2bf(float f) {
  unsigned u = __builtin_bit_cast(unsigned, f);
  unsigned r = (u + 0x7fffu + ((u >> 16) & 1u)) >> 16;  // RNE
  return (bfraw)r;
}
__device__ __forceinline__ float bf2f(bfraw u) {
  unsigned v = ((unsigned)u) << 16;
  return __builtin_bit_cast(float, v);
}

// ---------------------------------------------------------------------------
__global__ __launch_bounds__(256) void to_bf16(
    const float* __restrict__ in, bfraw* __restrict__ outv, int n) {
  int i = blockIdx.x * 256 + threadIdx.x;
  if (i < n) outv[i] = f2bf(in[i]);
}

// ---------------------------------------------------------------------------
// Bucket histogram: LDS-accumulate then flush (few global atomics).
// ---------------------------------------------------------------------------
__global__ __launch_bounds__(256) void bucket_hist(
    const int* __restrict__ dst, int* __restrict__ bcnt) {
  __shared__ int h[NB];
  for (int i = threadIdx.x; i < NB; i += 256) h[i] = 0;
  __syncthreads();
  for (int e = blockIdx.x * 256 + threadIdx.x; e < N_EDGES; e += 512 * 256)
    atomicAdd(&h[dst[e] >> BSHIFT], 1);
  __syncthreads();
  for (int i = threadIdx.x; i < NB; i += 256)
    if (h[i]) atomicAdd(&bcnt[i], h[i]);
}

// Single-block exclusive scan of NB bucket counts -> bucket_ptr[NB+1].
__global__ __launch_bounds__(256) void bucket_scan(
    const int* __restrict__ bcnt, int* __restrict__ bptr) {
  __shared__ int s[256];
  int tid = threadIdx.x;
  int base = tid * 8;
  int v[8];
  int tsum = 0;
#pragma unroll
  for (int i = 0; i < 8; ++i) {
    int g = base + i;
    v[i] = (g < NB) ? bcnt[g] : 0;
    tsum += v[i];
  }
  s[tid] = tsum;
  __syncthreads();
  for (int off = 1; off < 256; off <<= 1) {
    int t = (tid >= off) ? s[tid - off] : 0;
    __syncthreads();
    s[tid] += t;
    __syncthreads();
  }
  int run = s[tid] - tsum;
#pragma unroll
  for (int i = 0; i < 8; ++i) {
    int g = base + i;
    if (g < NB) bptr[g] = run;
    run += v[i];
  }
  if (tid == 255) bptr[NB] = s[255];
}

// ---------------------------------------------------------------------------
// Scatter (src,dst) pairs into bucket-contiguous staging. Writes within a
// bucket are sequential -> cachelines fill completely before eviction.
// ---------------------------------------------------------------------------
__global__ __launch_bounds__(256) void bucket_scatter(
    const int* __restrict__ src, const int* __restrict__ dst,
    const int* __restrict__ bptr, int* __restrict__ bcur,
    int2* __restrict__ staged) {
  int e = blockIdx.x * 256 + threadIdx.x;
  if (e >= N_EDGES) return;
  int d = dst[e];
  int b = d >> BSHIFT;
  int pos = atomicAdd(&bcur[b], 1);
  staged[bptr[b] + pos] = make_int2(src[e], d);
}

// ---------------------------------------------------------------------------
// Per-bucket fill: LDS node-count -> LDS scan -> emit row_ptr (free!) ->
// place src ids into the bucket's contiguous (L2-hot) sorted_src region.
// ---------------------------------------------------------------------------
__global__ __launch_bounds__(256) void bucket_fill(
    const int2* __restrict__ staged, const int* __restrict__ bptr,
    int* __restrict__ row_ptr, int* __restrict__ sorted_src) {
  __shared__ int s_cnt[BNODES];
  __shared__ int s_scan[BNODES];
  int b = blockIdx.x;
  int tid = threadIdx.x;
  int n0 = b << BSHIFT;
  int beg = bptr[b], end = bptr[b + 1];
  if (tid < BNODES) s_cnt[tid] = 0;
  __syncthreads();
  for (int i = beg + tid; i < end; i += 256)
    atomicAdd(&s_cnt[staged[i].y - n0], 1);
  __syncthreads();
  if (tid < BNODES) s_scan[tid] = s_cnt[tid];
  __syncthreads();
  for (int off = 1; off < BNODES; off <<= 1) {
    int t = (tid < BNODES && tid >= off) ? s_scan[tid - off] : 0;
    __syncthreads();
    if (tid < BNODES) s_scan[tid] += t;
    __syncthreads();
  }
  if (tid < BNODES) {
    int node = n0 + tid;
    int excl = s_scan[tid] - s_cnt[tid];
    if (node < N_NODES) row_ptr[node] = beg + excl;
    s_cnt[tid] = excl;  // reuse as relative cursor
  }
  if (b == 0 && tid == 0) row_ptr[N_NODES] = N_EDGES;
  __syncthreads();
  for (int i = beg + tid; i < end; i += 256) {
    int2 p = staged[i];
    int r = atomicAdd(&s_cnt[p.y - n0], 1);
    sorted_src[beg + r] = p.x;
  }
}

// ---------------------------------------------------------------------------
// Layer 1 fused: gather-mean(bf16 x) + lin_l + lin_r + relu -> h1 (bf16).
// 8 groups of 8 lanes; each lane owns 4 channels (ushort4, 8B loads);
// 2-deep unroll -> 16 edges in flight per wave.
// ---------------------------------------------------------------------------
__global__ __launch_bounds__(256) void layer1_fused(
    const float* __restrict__ x, const bfraw* __restrict__ xb,
    const int* __restrict__ row_ptr, const int* __restrict__ sorted_src,
    const float* __restrict__ w_l, const float* __restrict__ b_l,
    const float* __restrict__ w_r, bfraw* __restrict__ h1b) {
  __shared__ float s_wl[HID * 33];
  __shared__ float s_wr[HID * 33];
  __shared__ float s_mean[4][IN_DIM];
  __shared__ float s_x[4][IN_DIM];

  int tid = threadIdx.x;
  for (int idx = tid; idx < HID * IN_DIM; idx += 256) {
    int j = idx >> 5, f = idx & 31;
    s_wl[j * 33 + f] = w_l[idx];
    s_wr[j * 33 + f] = w_r[idx];
  }
  int w = tid >> 6, lane = tid & 63;
  int node = blockIdx.x * 4 + w;  // exact: 25000*4
  int q = lane & 7, g = lane >> 3;
  int rs = row_ptr[node];
  int deg = row_ptr[node + 1] - rs;
  if (lane < IN_DIM) s_x[w][lane] = x[node * IN_DIM + lane];

  float ax = 0.f, ay = 0.f, az = 0.f, aw = 0.f;
  float bx = 0.f, by = 0.f, bz = 0.f, bw = 0.f;
  int kk = g;
  for (; kk + 8 < deg; kk += 16) {
    int s0 = sorted_src[rs + kk];
    int s1 = sorted_src[rs + kk + 8];
    ushort4 u0 = *(const ushort4*)&xb[s0 * IN_DIM + 4 * q];
    ushort4 u1 = *(const ushort4*)&xb[s1 * IN_DIM + 4 * q];
    ax += bf2f(u0.x); ay += bf2f(u0.y); az += bf2f(u0.z); aw += bf2f(u0.w);
    bx += bf2f(u1.x); by += bf2f(u1.y); bz += bf2f(u1.z); bw += bf2f(u1.w);
  }
  if (kk < deg) {
    int s0 = sorted_src[rs + kk];
    ushort4 u0 = *(const ushort4*)&xb[s0 * IN_DIM + 4 * q];
    ax += bf2f(u0.x); ay += bf2f(u0.y); az += bf2f(u0.z); aw += bf2f(u0.w);
  }
  ax += bx; ay += by; az += bz; aw += bw;
#pragma unroll
  for (int off = 8; off < 64; off <<= 1) {
    ax += __shfl_xor(ax, off, 64);
    ay += __shfl_xor(ay, off, 64);
    az += __shfl_xor(az, off, 64);
    aw += __shfl_xor(aw, off, 64);
  }
  float rinv = 1.0f / fmaxf((float)deg, 1.0f);
  if (g == 0) {
    s_mean[w][4 * q]     = ax * rinv;
    s_mean[w][4 * q + 1] = ay * rinv;
    s_mean[w][4 * q + 2] = az * rinv;
    s_mean[w][4 * q + 3] = aw * rinv;
  }
  __syncthreads();

  int j = lane;
  float acc = b_l[j];
#pragma unroll
  for (int ff = 0; ff < IN_DIM; ++ff)
    acc += s_mean[w][ff] * s_wl[j * 33 + ff] + s_x[w][ff] * s_wr[j * 33 + ff];
  h1b[node * HID + j] = f2bf(fmaxf(acc, 0.0f));
}

// ---------------------------------------------------------------------------
// Layer 2 fused: gather-mean(bf16 h1) + lin_l + lin_r + relu + classifier.
// 4 groups of 16 lanes; each lane owns 4 channels (ushort4, 8B loads);
// 2-deep unroll -> 8 edges in flight per wave. Weights packed bf16 in LDS.
// ---------------------------------------------------------------------------
__global__ __launch_bounds__(256) void layer2_fused(
    const bfraw* __restrict__ h1b, const int* __restrict__ row_ptr,
    const int* __restrict__ sorted_src, const float* __restrict__ w_l,
    const float* __restrict__ b_l, const float* __restrict__ w_r,
    const float* __restrict__ wc, const float* __restrict__ bc,
    float* __restrict__ out) {
  __shared__ ushort2 s_wl[HID * 33];
  __shared__ ushort2 s_wr[HID * 33];
  __shared__ float s_mean[4][HID];
  __shared__ float s_h[4][HID];
  __shared__ float s_wc[HID];

  int tid = threadIdx.x;
  for (int idx = tid; idx < HID * HID / 2; idx += 256) {
    int j = idx >> 5;
    int p = idx & 31;
    float2 vl = *(const float2*)&w_l[j * HID + 2 * p];
    float2 vr = *(const float2*)&w_r[j * HID + 2 * p];
    s_wl[j * 33 + p] = make_ushort2(f2bf(vl.x), f2bf(vl.y));
    s_wr[j * 33 + p] = make_ushort2(f2bf(vr.x), f2bf(vr.y));
  }
  if (tid < HID) s_wc[tid] = wc[tid];

  int w = tid >> 6, lane = tid & 63;
  int node = blockIdx.x * 4 + w;
  int q = lane & 15, g = lane >> 4;
  int rs = row_ptr[node];
  int deg = row_ptr[node + 1] - rs;
  s_h[w][lane] = bf2f(h1b[node * HID + lane]);

  float ax = 0.f, ay = 0.f, az = 0.f, aw = 0.f;
  float bx = 0.f, by = 0.f, bz = 0.f, bw = 0.f;
  int kk = g;
  for (; kk + 4 < deg; kk += 8) {
    int s0 = sorted_src[rs + kk];
    int s1 = sorted_src[rs + kk + 4];
    ushort4 u0 = *(const ushort4*)&h1b[s0 * HID + 4 * q];
    ushort4 u1 = *(const ushort4*)&h1b[s1 * HID + 4 * q];
    ax += bf2f(u0.x); ay += bf2f(u0.y); az += bf2f(u0.z); aw += bf2f(u0.w);
    bx += bf2f(u1.x); by += bf2f(u1.y); bz += bf2f(u1.z); bw += bf2f(u1.w);
  }
  if (kk < deg) {
    int s0 = sorted_src[rs + kk];
    ushort4 u0 = *(const ushort4*)&h1b[s0 * HID + 4 * q];
    ax += bf2f(u0.x); ay += bf2f(u0.y); az += bf2f(u0.z); aw += bf2f(u0.w);
  }
  ax += bx; ay += by; az += bz; aw += bw;
#pragma unroll
  for (int off = 16; off < 64; off <<= 1) {
    ax += __shfl_xor(ax, off, 64);
    ay += __shfl_xor(ay, off, 64);
    az += __shfl_xor(az, off, 64);
    aw += __shfl_xor(aw, off, 64);
  }
  float rinv = 1.0f / fmaxf((float)deg, 1.0f);
  if (g == 0) {
    s_mean[w][4 * q]     = ax * rinv;
    s_mean[w][4 * q + 1] = ay * rinv;
    s_mean[w][4 * q + 2] = az * rinv;
    s_mean[w][4 * q + 3] = aw * rinv;
  }
  __syncthreads();

  int j = lane;
  float acc = b_l[j];
#pragma unroll
  for (int p = 0; p < HID / 2; ++p) {
    ushort2 wl = s_wl[j * 33 + p];
    ushort2 wr = s_wr[j * 33 + p];
    acc += s_mean[w][2 * p] * bf2f(wl.x) + s_mean[w][2 * p + 1] * bf2f(wl.y)
         + s_h[w][2 * p]   * bf2f(wr.x) + s_h[w][2 * p + 1]   * bf2f(wr.y);
  }
  float h2 = fmaxf(acc, 0.f);
  float contrib = h2 * s_wc[j];
#pragma unroll
  for (int off = 32; off > 0; off >>= 1)
    contrib += __shfl_down(contrib, off, 64);
  if (lane == 0) out[node] = contrib + bc[0];
}

// ---------------------------------------------------------------------------
extern "C" void kernel_launch(void* const* d_in, const int* in_sizes, int n_in,
                              void* d_out, int out_size, void* d_ws, size_t ws_size,
                              hipStream_t stream) {
  const float* x   = (const float*)d_in[0];
  const int*   ei  = (const int*)d_in[1];
  const float* w1l = (const float*)d_in[2];
  const float* b1l = (const float*)d_in[3];
  const float* w1r = (const float*)d_in[4];
  const float* w2l = (const float*)d_in[5];
  const float* b2l = (const float*)d_in[6];
  const float* w2r = (const float*)d_in[7];
  const float* wc  = (const float*)d_in[8];
  const float* bc  = (const float*)d_in[9];
  float* out = (float*)d_out;

  const int* src = ei;             // edge_index[0]
  const int* dst = ei + N_EDGES;   // edge_index[1]

  // workspace layout
  char* ws = (char*)d_ws;
  int*   row_ptr    = (int*)(ws + 0);          // 400,004 B
  int*   bucket_cnt = (int*)(ws + 400128);     // NB*4 = 6,252 B (also cursor)
  int*   bucket_ptr = (int*)(ws + 406528);     // (NB+1)*4 = 6,256 B
  int2*  staged     = (int2*)(ws + 412928);    // E*8 = 25.6 MB
  int*   sorted_src = (int*)(ws + 26012928);   // E*4 = 12.8 MB
  bfraw* xb         = (bfraw*)(ws + 38812928); // 6.4 MB
  bfraw* h1b        = (bfraw*)(ws + 45212928); // 12.8 MB
  // total 58,012,928 B

  to_bf16<<<(N_NODES * IN_DIM + 255) / 256, 256, 0, stream>>>(x, xb,
                                                              N_NODES * IN_DIM);
  hipMemsetAsync(bucket_cnt, 0, NB * sizeof(int), stream);
  bucket_hist<<<512, 256, 0, stream>>>(dst, bucket_cnt);
  bucket_scan<<<1, 256, 0, stream>>>(bucket_cnt, bucket_ptr);
  hipMemsetAsync(bucket_cnt, 0, NB * sizeof(int), stream);  // -> cursor
  bucket_scatter<<<(N_EDGES + 255) / 256, 256, 0, stream>>>(src, dst,
                                                            bucket_ptr,
                                                            bucket_cnt, staged);
  bucket_fill<<<NB, 256, 0, stream>>>(staged, bucket_ptr, row_ptr, sorted_src);
  layer1_fused<<<N_NODES / 4, 256, 0, stream>>>(x, xb, row_ptr, sorted_src,
                                                w1l, b1l, w1r, h1b);
  layer2_fused<<<N_NODES / 4, 256, 0, stream>>>(h1b, row_ptr, sorted_src,
                                                w2l, b2l, w2r, wc, bc, out);
}

// Round 5
// 310.602 us; speedup vs baseline: 2.4359x; 2.4359x over previous
//
#include <hip/hip_runtime.h>

#define N_NODES 100000
#define N_EDGES 3200000
#define IN_DIM 32
#define HID 64
#define BSHIFT 8
#define BNODES 256                              // nodes per bucket
#define NB ((N_NODES + BNODES - 1) / BNODES)    // 391 buckets
#define NWG 256                                 // WGs for count/place
#define CHUNK (N_EDGES / NWG)                   // 12500 edges per WG (exact)

typedef unsigned short bfraw;

__device__ __forceinline__ bfraw f2bf(float f) {
  unsigned u = __builtin_bit_cast(unsigned, f);
  unsigned r = (u + 0x7fffu + ((u >> 16) & 1u)) >> 16;  // RNE
  return (bfraw)r;
}
__device__ __forceinline__ float bf2f(bfraw u) {
  unsigned v = ((unsigned)u) << 16;
  return __builtin_bit_cast(float, v);
}

// ---------------------------------------------------------------------------
__global__ __launch_bounds__(256) void to_bf16(
    const float* __restrict__ in, bfraw* __restrict__ outv, int n) {
  int i = blockIdx.x * 256 + threadIdx.x;
  if (i < n) outv[i] = f2bf(in[i]);
}

// ---------------------------------------------------------------------------
// P1: per-WG bucket histogram of its edge chunk. counts[w][b] (contiguous/WG).
// ---------------------------------------------------------------------------
__global__ __launch_bounds__(256) void csr_count(
    const int* __restrict__ dst, int* __restrict__ counts) {
  __shared__ int h[NB];
  int w = blockIdx.x, tid = threadIdx.x;
  for (int i = tid; i < NB; i += 256) h[i] = 0;
  __syncthreads();
  int e0 = w * CHUNK;
  for (int i = tid; i < CHUNK; i += 256)
    atomicAdd(&h[dst[e0 + i] >> BSHIFT], 1);
  __syncthreads();
  for (int i = tid; i < NB; i += 256) counts[w * NB + i] = h[i];
}

// ---------------------------------------------------------------------------
// P2a: per bucket b, exclusive scan of counts[·][b] over w (in place);
// total -> btot[b].
// ---------------------------------------------------------------------------
__global__ __launch_bounds__(256) void csr_scan_w(
    int* __restrict__ counts, int* __restrict__ btot) {
  __shared__ int s[256];
  int b = blockIdx.x, tid = threadIdx.x;
  int v = counts[tid * NB + b];
  s[tid] = v;
  __syncthreads();
  for (int off = 1; off < 256; off <<= 1) {
    int t = (tid >= off) ? s[tid - off] : 0;
    __syncthreads();
    s[tid] += t;
    __syncthreads();
  }
  counts[tid * NB + b] = s[tid] - v;  // exclusive over w
  if (tid == 255) btot[b] = s[255];
}

// P2b: exclusive scan of btot[NB] -> bbase[NB+1] (1 WG, 2 elems/thread).
__global__ __launch_bounds__(256) void csr_scan_b(
    const int* __restrict__ btot, int* __restrict__ bbase) {
  __shared__ int s[256];
  int tid = threadIdx.x;
  int g0 = tid * 2, g1 = tid * 2 + 1;
  int v0 = (g0 < NB) ? btot[g0] : 0;
  int v1 = (g1 < NB) ? btot[g1] : 0;
  int tsum = v0 + v1;
  s[tid] = tsum;
  __syncthreads();
  for (int off = 1; off < 256; off <<= 1) {
    int t = (tid >= off) ? s[tid - off] : 0;
    __syncthreads();
    s[tid] += t;
    __syncthreads();
  }
  int run = s[tid] - tsum;
  if (g0 < NB) bbase[g0] = run;
  if (g1 < NB) bbase[g1] = run + v0;
  if (tid == 0) bbase[NB] = N_EDGES;
}

// ---------------------------------------------------------------------------
// P3: WG w re-streams its chunk; LDS cursors preloaded with EXACT global
// offsets (bbase[b] + counts[w][b]) -> zero global atomics; each (w,b)
// segment is contiguous and written by exactly one WG.
// packed value: (src << 8) | (dst & 255)   (src < 2^17)
// ---------------------------------------------------------------------------
__global__ __launch_bounds__(256) void csr_place(
    const int* __restrict__ src, const int* __restrict__ dst,
    const int* __restrict__ counts, const int* __restrict__ bbase,
    unsigned* __restrict__ staged) {
  __shared__ int cur[NB];
  int w = blockIdx.x, tid = threadIdx.x;
  for (int i = tid; i < NB; i += 256) cur[i] = bbase[i] + counts[w * NB + i];
  __syncthreads();
  int e0 = w * CHUNK;
  for (int i = tid; i < CHUNK; i += 256) {
    int d = dst[e0 + i];
    int b = d >> BSHIFT;
    int pos = atomicAdd(&cur[b], 1);
    staged[pos] = ((unsigned)src[e0 + i] << 8) | (unsigned)(d & (BNODES - 1));
  }
}

// ---------------------------------------------------------------------------
// P4: WG per bucket: LDS node histogram + scan -> row_ptr (free) -> place
// src ids into the bucket's contiguous (single-WG-owned) sorted_src region.
// ---------------------------------------------------------------------------
__global__ __launch_bounds__(256) void csr_fill(
    const unsigned* __restrict__ staged, const int* __restrict__ bbase,
    int* __restrict__ row_ptr, int* __restrict__ sorted_src) {
  __shared__ int s_cnt[BNODES];
  __shared__ int s_scan[BNODES];
  int b = blockIdx.x, tid = threadIdx.x;
  int n0 = b << BSHIFT;
  int beg = bbase[b], end = bbase[b + 1];
  s_cnt[tid] = 0;
  __syncthreads();
  for (int i = beg + tid; i < end; i += 256)
    atomicAdd(&s_cnt[staged[i] & (BNODES - 1)], 1);
  __syncthreads();
  int v = s_cnt[tid];
  s_scan[tid] = v;
  __syncthreads();
  for (int off = 1; off < BNODES; off <<= 1) {
    int t = (tid >= off) ? s_scan[tid - off] : 0;
    __syncthreads();
    s_scan[tid] += t;
    __syncthreads();
  }
  int excl = s_scan[tid] - v;
  int node = n0 + tid;
  if (node < N_NODES) row_ptr[node] = beg + excl;
  if (b == 0 && tid == 0) row_ptr[N_NODES] = N_EDGES;
  s_cnt[tid] = excl;  // relative cursor
  __syncthreads();
  for (int i = beg + tid; i < end; i += 256) {
    unsigned p = staged[i];
    int r = atomicAdd(&s_cnt[p & (BNODES - 1)], 1);
    sorted_src[beg + r] = (int)(p >> 8);
  }
}

// ---------------------------------------------------------------------------
// Layer 1 fused: gather-mean(bf16 x) + lin_l + lin_r + relu -> h1 (bf16).
// 8 groups of 8 lanes; each lane owns 4 channels (ushort4, 8B loads);
// 2-deep unroll -> 16 edges in flight per wave.
// ---------------------------------------------------------------------------
__global__ __launch_bounds__(256) void layer1_fused(
    const float* __restrict__ x, const bfraw* __restrict__ xb,
    const int* __restrict__ row_ptr, const int* __restrict__ sorted_src,
    const float* __restrict__ w_l, const float* __restrict__ b_l,
    const float* __restrict__ w_r, bfraw* __restrict__ h1b) {
  __shared__ float s_wl[HID * 33];
  __shared__ float s_wr[HID * 33];
  __shared__ float s_mean[4][IN_DIM];
  __shared__ float s_x[4][IN_DIM];

  int tid = threadIdx.x;
  for (int idx = tid; idx < HID * IN_DIM; idx += 256) {
    int j = idx >> 5, f = idx & 31;
    s_wl[j * 33 + f] = w_l[idx];
    s_wr[j * 33 + f] = w_r[idx];
  }
  int w = tid >> 6, lane = tid & 63;
  int node = blockIdx.x * 4 + w;  // exact: 25000*4
  int q = lane & 7, g = lane >> 3;
  int rs = row_ptr[node];
  int deg = row_ptr[node + 1] - rs;
  if (lane < IN_DIM) s_x[w][lane] = x[node * IN_DIM + lane];

  float ax = 0.f, ay = 0.f, az = 0.f, aw = 0.f;
  float bx = 0.f, by = 0.f, bz = 0.f, bw = 0.f;
  int kk = g;
  for (; kk + 8 < deg; kk += 16) {
    int s0 = sorted_src[rs + kk];
    int s1 = sorted_src[rs + kk + 8];
    ushort4 u0 = *(const ushort4*)&xb[s0 * IN_DIM + 4 * q];
    ushort4 u1 = *(const ushort4*)&xb[s1 * IN_DIM + 4 * q];
    ax += bf2f(u0.x); ay += bf2f(u0.y); az += bf2f(u0.z); aw += bf2f(u0.w);
    bx += bf2f(u1.x); by += bf2f(u1.y); bz += bf2f(u1.z); bw += bf2f(u1.w);
  }
  if (kk < deg) {
    int s0 = sorted_src[rs + kk];
    ushort4 u0 = *(const ushort4*)&xb[s0 * IN_DIM + 4 * q];
    ax += bf2f(u0.x); ay += bf2f(u0.y); az += bf2f(u0.z); aw += bf2f(u0.w);
  }
  ax += bx; ay += by; az += bz; aw += bw;
#pragma unroll
  for (int off = 8; off < 64; off <<= 1) {
    ax += __shfl_xor(ax, off, 64);
    ay += __shfl_xor(ay, off, 64);
    az += __shfl_xor(az, off, 64);
    aw += __shfl_xor(aw, off, 64);
  }
  float rinv = 1.0f / fmaxf((float)deg, 1.0f);
  if (g == 0) {
    s_mean[w][4 * q]     = ax * rinv;
    s_mean[w][4 * q + 1] = ay * rinv;
    s_mean[w][4 * q + 2] = az * rinv;
    s_mean[w][4 * q + 3] = aw * rinv;
  }
  __syncthreads();

  int j = lane;
  float acc = b_l[j];
#pragma unroll
  for (int ff = 0; ff < IN_DIM; ++ff)
    acc += s_mean[w][ff] * s_wl[j * 33 + ff] + s_x[w][ff] * s_wr[j * 33 + ff];
  h1b[node * HID + j] = f2bf(fmaxf(acc, 0.0f));
}

// ---------------------------------------------------------------------------
// Layer 2 fused: gather-mean(bf16 h1) + lin_l + lin_r + relu + classifier.
// 4 groups of 16 lanes; each lane owns 4 channels (ushort4, 8B loads);
// 2-deep unroll -> 8 edges in flight per wave. Weights packed bf16 in LDS.
// ---------------------------------------------------------------------------
__global__ __launch_bounds__(256) void layer2_fused(
    const bfraw* __restrict__ h1b, const int* __restrict__ row_ptr,
    const int* __restrict__ sorted_src, const float* __restrict__ w_l,
    const float* __restrict__ b_l, const float* __restrict__ w_r,
    const float* __restrict__ wc, const float* __restrict__ bc,
    float* __restrict__ out) {
  __shared__ ushort2 s_wl[HID * 33];
  __shared__ ushort2 s_wr[HID * 33];
  __shared__ float s_mean[4][HID];
  __shared__ float s_h[4][HID];
  __shared__ float s_wc[HID];

  int tid = threadIdx.x;
  for (int idx = tid; idx < HID * HID / 2; idx += 256) {
    int j = idx >> 5;
    int p = idx & 31;
    float2 vl = *(const float2*)&w_l[j * HID + 2 * p];
    float2 vr = *(const float2*)&w_r[j * HID + 2 * p];
    s_wl[j * 33 + p] = make_ushort2(f2bf(vl.x), f2bf(vl.y));
    s_wr[j * 33 + p] = make_ushort2(f2bf(vr.x), f2bf(vr.y));
  }
  if (tid < HID) s_wc[tid] = wc[tid];

  int w = tid >> 6, lane = tid & 63;
  int node = blockIdx.x * 4 + w;
  int q = lane & 15, g = lane >> 4;
  int rs = row_ptr[node];
  int deg = row_ptr[node + 1] - rs;
  s_h[w][lane] = bf2f(h1b[node * HID + lane]);

  float ax = 0.f, ay = 0.f, az = 0.f, aw = 0.f;
  float bx = 0.f, by = 0.f, bz = 0.f, bw = 0.f;
  int kk = g;
  for (; kk + 4 < deg; kk += 8) {
    int s0 = sorted_src[rs + kk];
    int s1 = sorted_src[rs + kk + 4];
    ushort4 u0 = *(const ushort4*)&h1b[s0 * HID + 4 * q];
    ushort4 u1 = *(const ushort4*)&h1b[s1 * HID + 4 * q];
    ax += bf2f(u0.x); ay += bf2f(u0.y); az += bf2f(u0.z); aw += bf2f(u0.w);
    bx += bf2f(u1.x); by += bf2f(u1.y); bz += bf2f(u1.z); bw += bf2f(u1.w);
  }
  if (kk < deg) {
    int s0 = sorted_src[rs + kk];
    ushort4 u0 = *(const ushort4*)&h1b[s0 * HID + 4 * q];
    ax += bf2f(u0.x); ay += bf2f(u0.y); az += bf2f(u0.z); aw += bf2f(u0.w);
  }
  ax += bx; ay += by; az += bz; aw += bw;
#pragma unroll
  for (int off = 16; off < 64; off <<= 1) {
    ax += __shfl_xor(ax, off, 64);
    ay += __shfl_xor(ay, off, 64);
    az += __shfl_xor(az, off, 64);
    aw += __shfl_xor(aw, off, 64);
  }
  float rinv = 1.0f / fmaxf((float)deg, 1.0f);
  if (g == 0) {
    s_mean[w][4 * q]     = ax * rinv;
    s_mean[w][4 * q + 1] = ay * rinv;
    s_mean[w][4 * q + 2] = az * rinv;
    s_mean[w][4 * q + 3] = aw * rinv;
  }
  __syncthreads();

  int j = lane;
  float acc = b_l[j];
#pragma unroll
  for (int p = 0; p < HID / 2; ++p) {
    ushort2 wl = s_wl[j * 33 + p];
    ushort2 wr = s_wr[j * 33 + p];
    acc += s_mean[w][2 * p] * bf2f(wl.x) + s_mean[w][2 * p + 1] * bf2f(wl.y)
         + s_h[w][2 * p]   * bf2f(wr.x) + s_h[w][2 * p + 1]   * bf2f(wr.y);
  }
  float h2 = fmaxf(acc, 0.f);
  float contrib = h2 * s_wc[j];
#pragma unroll
  for (int off = 32; off > 0; off >>= 1)
    contrib += __shfl_down(contrib, off, 64);
  if (lane == 0) out[node] = contrib + bc[0];
}

// ---------------------------------------------------------------------------
extern "C" void kernel_launch(void* const* d_in, const int* in_sizes, int n_in,
                              void* d_out, int out_size, void* d_ws, size_t ws_size,
                              hipStream_t stream) {
  const float* x   = (const float*)d_in[0];
  const int*   ei  = (const int*)d_in[1];
  const float* w1l = (const float*)d_in[2];
  const float* b1l = (const float*)d_in[3];
  const float* w1r = (const float*)d_in[4];
  const float* w2l = (const float*)d_in[5];
  const float* b2l = (const float*)d_in[6];
  const float* w2r = (const float*)d_in[7];
  const float* wc  = (const float*)d_in[8];
  const float* bc  = (const float*)d_in[9];
  float* out = (float*)d_out;

  const int* src = ei;             // edge_index[0]
  const int* dst = ei + N_EDGES;   // edge_index[1]

  // workspace layout
  char* ws = (char*)d_ws;
  int*      row_ptr    = (int*)(ws + 0);          // 400,004 B
  int*      counts     = (int*)(ws + 400128);     // NWG*NB*4 = 400,384 B
  int*      btot       = (int*)(ws + 800768);     // NB*4 = 1,564 B
  int*      bbase      = (int*)(ws + 802560);     // (NB+1)*4 = 1,568 B
  unsigned* staged     = (unsigned*)(ws + 804352);// E*4 = 12.8 MB
  int*      sorted_src = (int*)(ws + 13604352);   // E*4 = 12.8 MB
  bfraw*    xb         = (bfraw*)(ws + 26404352); // 6.4 MB
  bfraw*    h1b        = (bfraw*)(ws + 32804352); // 12.8 MB
  // total 45,604,352 B

  to_bf16<<<(N_NODES * IN_DIM + 255) / 256, 256, 0, stream>>>(x, xb,
                                                              N_NODES * IN_DIM);
  csr_count<<<NWG, 256, 0, stream>>>(dst, counts);
  csr_scan_w<<<NB, 256, 0, stream>>>(counts, btot);
  csr_scan_b<<<1, 256, 0, stream>>>(btot, bbase);
  csr_place<<<NWG, 256, 0, stream>>>(src, dst, counts, bbase, staged);
  csr_fill<<<NB, 256, 0, stream>>>(staged, bbase, row_ptr, sorted_src);
  layer1_fused<<<N_NODES / 4, 256, 0, stream>>>(x, xb, row_ptr, sorted_src,
                                                w1l, b1l, w1r, h1b);
  layer2_fused<<<N_NODES / 4, 256, 0, stream>>>(h1b, row_ptr, sorted_src,
                                                w2l, b2l, w2r, wc, bc, out);
}

// Round 6
// 223.784 us; speedup vs baseline: 3.3810x; 1.3880x over previous
//
#include <hip/hip_runtime.h>

#define N_NODES 100000
#define N_EDGES 3200000
#define IN_DIM 32
#define HID 64
#define BSHIFT 8
#define BNODES 256                              // nodes per bucket
#define NB ((N_NODES + BNODES - 1) / BNODES)    // 391 buckets
#define NWG 256                                 // WGs for count/place
#define CHUNK (N_EDGES / NWG)                   // 12500 edges per WG (exact)

typedef unsigned short u16;
typedef _Float16 h2 __attribute__((ext_vector_type(2)));
typedef _Float16 half8 __attribute__((ext_vector_type(8)));
typedef float float4v __attribute__((ext_vector_type(4)));

__device__ __forceinline__ h2 as_h2(unsigned u) {
  return __builtin_bit_cast(h2, u);
}
__device__ __forceinline__ unsigned as_u(h2 v) {
  return __builtin_bit_cast(unsigned, v);
}
__device__ __forceinline__ h2 shfl_xor_h2(h2 v, int m) {
  int i = __builtin_bit_cast(int, v);
  i = __shfl_xor(i, m, 64);
  return __builtin_bit_cast(h2, i);
}
__device__ __forceinline__ u16 f2h(float f) {
  _Float16 h = (_Float16)f;
  return __builtin_bit_cast(u16, h);
}

// ---------------------------------------------------------------------------
__global__ __launch_bounds__(256) void to_f16(
    const float* __restrict__ in, u16* __restrict__ outv, int n) {
  int i = blockIdx.x * 256 + threadIdx.x;
  if (i < n) outv[i] = f2h(in[i]);
}

// ---------------------------------------------------------------------------
// CSR build (R5 pipeline, unchanged): per-WG count -> scans -> exact-offset
// place (zero global atomics) -> per-bucket fill (emits row_ptr for free).
// ---------------------------------------------------------------------------
__global__ __launch_bounds__(256) void csr_count(
    const int* __restrict__ dst, int* __restrict__ counts) {
  __shared__ int h[NB];
  int w = blockIdx.x, tid = threadIdx.x;
  for (int i = tid; i < NB; i += 256) h[i] = 0;
  __syncthreads();
  int e0 = w * CHUNK;
  for (int i = tid; i < CHUNK; i += 256)
    atomicAdd(&h[dst[e0 + i] >> BSHIFT], 1);
  __syncthreads();
  for (int i = tid; i < NB; i += 256) counts[w * NB + i] = h[i];
}

__global__ __launch_bounds__(256) void csr_scan_w(
    int* __restrict__ counts, int* __restrict__ btot) {
  __shared__ int s[256];
  int b = blockIdx.x, tid = threadIdx.x;
  int v = counts[tid * NB + b];
  s[tid] = v;
  __syncthreads();
  for (int off = 1; off < 256; off <<= 1) {
    int t = (tid >= off) ? s[tid - off] : 0;
    __syncthreads();
    s[tid] += t;
    __syncthreads();
  }
  counts[tid * NB + b] = s[tid] - v;
  if (tid == 255) btot[b] = s[255];
}

__global__ __launch_bounds__(256) void csr_scan_b(
    const int* __restrict__ btot, int* __restrict__ bbase) {
  __shared__ int s[256];
  int tid = threadIdx.x;
  int g0 = tid * 2, g1 = tid * 2 + 1;
  int v0 = (g0 < NB) ? btot[g0] : 0;
  int v1 = (g1 < NB) ? btot[g1] : 0;
  int tsum = v0 + v1;
  s[tid] = tsum;
  __syncthreads();
  for (int off = 1; off < 256; off <<= 1) {
    int t = (tid >= off) ? s[tid - off] : 0;
    __syncthreads();
    s[tid] += t;
    __syncthreads();
  }
  int run = s[tid] - tsum;
  if (g0 < NB) bbase[g0] = run;
  if (g1 < NB) bbase[g1] = run + v0;
  if (tid == 0) bbase[NB] = N_EDGES;
}

__global__ __launch_bounds__(256) void csr_place(
    const int* __restrict__ src, const int* __restrict__ dst,
    const int* __restrict__ counts, const int* __restrict__ bbase,
    unsigned* __restrict__ staged) {
  __shared__ int cur[NB];
  int w = blockIdx.x, tid = threadIdx.x;
  for (int i = tid; i < NB; i += 256) cur[i] = bbase[i] + counts[w * NB + i];
  __syncthreads();
  int e0 = w * CHUNK;
  for (int i = tid; i < CHUNK; i += 256) {
    int d = dst[e0 + i];
    int b = d >> BSHIFT;
    int pos = atomicAdd(&cur[b], 1);
    staged[pos] = ((unsigned)src[e0 + i] << 8) | (unsigned)(d & (BNODES - 1));
  }
}

__global__ __launch_bounds__(256) void csr_fill(
    const unsigned* __restrict__ staged, const int* __restrict__ bbase,
    int* __restrict__ row_ptr, int* __restrict__ sorted_src) {
  __shared__ int s_cnt[BNODES];
  __shared__ int s_scan[BNODES];
  int b = blockIdx.x, tid = threadIdx.x;
  int n0 = b << BSHIFT;
  int beg = bbase[b], end = bbase[b + 1];
  s_cnt[tid] = 0;
  __syncthreads();
  for (int i = beg + tid; i < end; i += 256)
    atomicAdd(&s_cnt[staged[i] & (BNODES - 1)], 1);
  __syncthreads();
  int v = s_cnt[tid];
  s_scan[tid] = v;
  __syncthreads();
  for (int off = 1; off < BNODES; off <<= 1) {
    int t = (tid >= off) ? s_scan[tid - off] : 0;
    __syncthreads();
    s_scan[tid] += t;
    __syncthreads();
  }
  int excl = s_scan[tid] - v;
  int node = n0 + tid;
  if (node < N_NODES) row_ptr[node] = beg + excl;
  if (b == 0 && tid == 0) row_ptr[N_NODES] = N_EDGES;
  s_cnt[tid] = excl;
  __syncthreads();
  for (int i = beg + tid; i < end; i += 256) {
    unsigned p = staged[i];
    int r = atomicAdd(&s_cnt[p & (BNODES - 1)], 1);
    sorted_src[beg + r] = (int)(p >> 8);
  }
}

// ---------------------------------------------------------------------------
// Layer 1: 16 nodes/block, 4 waves. Gather-mean (f16, packed adds) into
// s_feat[n][0:32]; root x into s_feat[n][32:64]. Epilogue: MFMA
// C[16x64] = feat[16x64] . [w1l;w1r][64x64], +bias, relu -> h1h (f16).
// K-mapping k = 32t + 8g + i applied identically to A and B (permutation
// cancels); C layout col=lane&15, row=(lane>>4)*4+reg (HW-verified).
// ---------------------------------------------------------------------------
#define F1 72  // padded feat stride (f16 elems): 144B rows, conflict-benign
__global__ __launch_bounds__(256) void layer1_fused(
    const u16* __restrict__ xh, const int* __restrict__ row_ptr,
    const int* __restrict__ sorted_src, const float* __restrict__ w_l,
    const float* __restrict__ b_l, const float* __restrict__ w_r,
    u16* __restrict__ h1h) {
  __shared__ __align__(16) u16 s_wl[HID * IN_DIM];
  __shared__ __align__(16) u16 s_wr[HID * IN_DIM];
  __shared__ __align__(16) u16 s_feat[16 * F1];

  int tid = threadIdx.x;
  for (int idx = tid; idx < HID * IN_DIM; idx += 256) {
    s_wl[idx] = f2h(w_l[idx]);
    s_wr[idx] = f2h(w_r[idx]);
  }
  int w = tid >> 6, lane = tid & 63;
  int q = lane & 7, g = lane >> 3;     // 8 groups of 8 lanes; lane owns ch 4q..4q+3

  for (int m = 0; m < 4; ++m) {
    int nl = 4 * w + m;
    int node = blockIdx.x * 16 + nl;
    int rs = row_ptr[node];
    int deg = row_ptr[node + 1] - rs;
    h2 a0{}, a1{}, b0{}, b1{};
    int kk = g;
    for (; kk + 8 < deg; kk += 16) {
      int s0 = sorted_src[rs + kk];
      int s1 = sorted_src[rs + kk + 8];
      uint2 u0 = *(const uint2*)&xh[s0 * IN_DIM + 4 * q];
      uint2 u1 = *(const uint2*)&xh[s1 * IN_DIM + 4 * q];
      a0 += as_h2(u0.x); a1 += as_h2(u0.y);
      b0 += as_h2(u1.x); b1 += as_h2(u1.y);
    }
    if (kk < deg) {
      int s0 = sorted_src[rs + kk];
      uint2 u0 = *(const uint2*)&xh[s0 * IN_DIM + 4 * q];
      a0 += as_h2(u0.x); a1 += as_h2(u0.y);
    }
    a0 += b0; a1 += b1;
    a0 += shfl_xor_h2(a0, 8);  a1 += shfl_xor_h2(a1, 8);
    a0 += shfl_xor_h2(a0, 16); a1 += shfl_xor_h2(a1, 16);
    a0 += shfl_xor_h2(a0, 32); a1 += shfl_xor_h2(a1, 32);
    if (g == 0) {
      float rinv = 1.0f / fmaxf((float)deg, 1.0f);
      h2 o0, o1;
      o0.x = (_Float16)((float)a0.x * rinv); o0.y = (_Float16)((float)a0.y * rinv);
      o1.x = (_Float16)((float)a1.x * rinv); o1.y = (_Float16)((float)a1.y * rinv);
      *(uint2*)&s_feat[nl * F1 + 4 * q] = make_uint2(as_u(o0), as_u(o1));
    }
  }
  // root x copy: wave w covers its 4 nodes; 16 lanes x 2ch each
  {
    int nm = lane >> 4, q2 = lane & 15;
    int nl = 4 * w + nm;
    int node = blockIdx.x * 16 + nl;
    unsigned ux = *(const unsigned*)&xh[node * IN_DIM + 2 * q2];
    *(unsigned*)&s_feat[nl * F1 + IN_DIM + 2 * q2] = ux;
  }
  __syncthreads();

  // MFMA epilogue: wave w computes out cols 16w..16w+15 for all 16 nodes
  int q16 = lane & 15, g4 = lane >> 4;
  int j = 16 * w + q16;
  half8 a0f = *(const half8*)&s_feat[q16 * F1 + 8 * g4];
  half8 a1f = *(const half8*)&s_feat[q16 * F1 + 32 + 8 * g4];
  half8 b0f = *(const half8*)&s_wl[j * IN_DIM + 8 * g4];
  half8 b1f = *(const half8*)&s_wr[j * IN_DIM + 8 * g4];
  float4v acc = {};
  acc = __builtin_amdgcn_mfma_f32_16x16x32_f16(a0f, b0f, acc, 0, 0, 0);
  acc = __builtin_amdgcn_mfma_f32_16x16x32_f16(a1f, b1f, acc, 0, 0, 0);
  float bj = b_l[j];
#pragma unroll
  for (int reg = 0; reg < 4; ++reg) {
    int nl = 4 * g4 + reg;
    float v = fmaxf(acc[reg] + bj, 0.0f);
    h1h[(blockIdx.x * 16 + nl) * HID + j] = f2h(v);
  }
}

// ---------------------------------------------------------------------------
// Layer 2: 16 nodes/block, 4 waves. Gather-mean(f16 h1) into s_feat[n][0:64],
// root h1 into s_feat[n][64:128]. Epilogue: MFMA C[16x64] =
// feat[16x128] . [w2l;w2r][128x64], +bias, relu, classifier dot -> out.
// ---------------------------------------------------------------------------
#define F2 136  // padded feat stride (f16): 272B rows
__global__ __launch_bounds__(256) void layer2_fused(
    const u16* __restrict__ h1h, const int* __restrict__ row_ptr,
    const int* __restrict__ sorted_src, const float* __restrict__ w_l,
    const float* __restrict__ b_l, const float* __restrict__ w_r,
    const float* __restrict__ wc, const float* __restrict__ bc,
    float* __restrict__ out) {
  __shared__ __align__(16) u16 s_wl[HID * HID];
  __shared__ __align__(16) u16 s_wr[HID * HID];
  __shared__ __align__(16) u16 s_feat[16 * F2];
  __shared__ float s_wc[HID];
  __shared__ float s_out[16];

  int tid = threadIdx.x;
  for (int idx = tid; idx < HID * HID; idx += 256) {
    s_wl[idx] = f2h(w_l[idx]);
    s_wr[idx] = f2h(w_r[idx]);
  }
  if (tid < HID) s_wc[tid] = wc[tid];
  if (tid < 16) s_out[tid] = bc[0];

  int w = tid >> 6, lane = tid & 63;
  int q = lane & 15, g = lane >> 4;   // 4 groups of 16 lanes; lane owns ch 4q..4q+3

  for (int m = 0; m < 4; ++m) {
    int nl = 4 * w + m;
    int node = blockIdx.x * 16 + nl;
    int rs = row_ptr[node];
    int deg = row_ptr[node + 1] - rs;
    h2 a0{}, a1{}, b0{}, b1{};
    int kk = g;
    for (; kk + 4 < deg; kk += 8) {
      int s0 = sorted_src[rs + kk];
      int s1 = sorted_src[rs + kk + 4];
      uint2 u0 = *(const uint2*)&h1h[s0 * HID + 4 * q];
      uint2 u1 = *(const uint2*)&h1h[s1 * HID + 4 * q];
      a0 += as_h2(u0.x); a1 += as_h2(u0.y);
      b0 += as_h2(u1.x); b1 += as_h2(u1.y);
    }
    if (kk < deg) {
      int s0 = sorted_src[rs + kk];
      uint2 u0 = *(const uint2*)&h1h[s0 * HID + 4 * q];
      a0 += as_h2(u0.x); a1 += as_h2(u0.y);
    }
    a0 += b0; a1 += b1;
    a0 += shfl_xor_h2(a0, 16); a1 += shfl_xor_h2(a1, 16);
    a0 += shfl_xor_h2(a0, 32); a1 += shfl_xor_h2(a1, 32);
    if (g == 0) {
      float rinv = 1.0f / fmaxf((float)deg, 1.0f);
      h2 o0, o1;
      o0.x = (_Float16)((float)a0.x * rinv); o0.y = (_Float16)((float)a0.y * rinv);
      o1.x = (_Float16)((float)a1.x * rinv); o1.y = (_Float16)((float)a1.y * rinv);
      *(uint2*)&s_feat[nl * F2 + 4 * q] = make_uint2(as_u(o0), as_u(o1));
    }
  }
  // root h1 copy: wave w covers its 4 nodes; 16 lanes x 4ch each
  {
    int nm = lane >> 4, q2 = lane & 15;
    int nl = 4 * w + nm;
    int node = blockIdx.x * 16 + nl;
    uint2 uh = *(const uint2*)&h1h[node * HID + 4 * q2];
    *(uint2*)&s_feat[nl * F2 + HID + 4 * q2] = uh;
  }
  __syncthreads();

  // MFMA epilogue
  int q16 = lane & 15, g4 = lane >> 4;
  int j = 16 * w + q16;
  float4v acc = {};
#pragma unroll
  for (int t = 0; t < 4; ++t) {
    half8 af = *(const half8*)&s_feat[q16 * F2 + 32 * t + 8 * g4];
    half8 bf;
    if (t < 2)
      bf = *(const half8*)&s_wl[j * HID + 32 * t + 8 * g4];
    else
      bf = *(const half8*)&s_wr[j * HID + 32 * (t - 2) + 8 * g4];
    acc = __builtin_amdgcn_mfma_f32_16x16x32_f16(af, bf, acc, 0, 0, 0);
  }
  float bj = b_l[j];
  float wcj = s_wc[j];
#pragma unroll
  for (int reg = 0; reg < 4; ++reg) {
    float v = fmaxf(acc[reg] + bj, 0.0f) * wcj;
    v += __shfl_xor(v, 1, 64);
    v += __shfl_xor(v, 2, 64);
    v += __shfl_xor(v, 4, 64);
    v += __shfl_xor(v, 8, 64);
    if (q16 == 0) atomicAdd(&s_out[4 * g4 + reg], v);
  }
  __syncthreads();
  if (tid < 16) out[blockIdx.x * 16 + tid] = s_out[tid];
}

// ---------------------------------------------------------------------------
extern "C" void kernel_launch(void* const* d_in, const int* in_sizes, int n_in,
                              void* d_out, int out_size, void* d_ws, size_t ws_size,
                              hipStream_t stream) {
  const float* x   = (const float*)d_in[0];
  const int*   ei  = (const int*)d_in[1];
  const float* w1l = (const float*)d_in[2];
  const float* b1l = (const float*)d_in[3];
  const float* w1r = (const float*)d_in[4];
  const float* w2l = (const float*)d_in[5];
  const float* b2l = (const float*)d_in[6];
  const float* w2r = (const float*)d_in[7];
  const float* wc  = (const float*)d_in[8];
  const float* bc  = (const float*)d_in[9];
  float* out = (float*)d_out;

  const int* src = ei;             // edge_index[0]
  const int* dst = ei + N_EDGES;   // edge_index[1]

  // workspace layout
  char* ws = (char*)d_ws;
  int*      row_ptr    = (int*)(ws + 0);          // 400,004 B
  int*      counts     = (int*)(ws + 400128);     // NWG*NB*4 = 400,384 B
  int*      btot       = (int*)(ws + 800768);     // 1,564 B
  int*      bbase      = (int*)(ws + 802560);     // 1,568 B
  unsigned* staged     = (unsigned*)(ws + 804352);// E*4 = 12.8 MB
  int*      sorted_src = (int*)(ws + 13604352);   // E*4 = 12.8 MB
  u16*      xh         = (u16*)(ws + 26404352);   // 6.4 MB
  u16*      h1h        = (u16*)(ws + 32804352);   // 12.8 MB
  // total 45,604,352 B

  to_f16<<<(N_NODES * IN_DIM + 255) / 256, 256, 0, stream>>>(x, xh,
                                                             N_NODES * IN_DIM);
  csr_count<<<NWG, 256, 0, stream>>>(dst, counts);
  csr_scan_w<<<NB, 256, 0, stream>>>(counts, btot);
  csr_scan_b<<<1, 256, 0, stream>>>(btot, bbase);
  csr_place<<<NWG, 256, 0, stream>>>(src, dst, counts, bbase, staged);
  csr_fill<<<NB, 256, 0, stream>>>(staged, bbase, row_ptr, sorted_src);
  layer1_fused<<<N_NODES / 16, 256, 0, stream>>>(xh, row_ptr, sorted_src,
                                                 w1l, b1l, w1r, h1h);
  layer2_fused<<<N_NODES / 16, 256, 0, stream>>>(h1h, row_ptr, sorted_src,
                                                 w2l, b2l, w2r, wc, bc, out);
}

// Round 7
// 209.630 us; speedup vs baseline: 3.6092x; 1.0675x over previous
//
#include <hip/hip_runtime.h>

#define N_NODES 100000
#define N_EDGES 3200000
#define IN_DIM 32
#define HID 64
#define BSHIFT 8
#define BNODES 256                              // nodes per bucket
#define NB ((N_NODES + BNODES - 1) / BNODES)    // 391 buckets
#define NWG 256                                 // WGs for count/place
#define CHUNK (N_EDGES / NWG)                   // 12500 edges per WG (exact)

typedef unsigned short u16;
typedef _Float16 h2 __attribute__((ext_vector_type(2)));
typedef _Float16 half8 __attribute__((ext_vector_type(8)));
typedef float float4v __attribute__((ext_vector_type(4)));

__device__ __forceinline__ h2 as_h2(unsigned u) {
  return __builtin_bit_cast(h2, u);
}
__device__ __forceinline__ unsigned as_u(h2 v) {
  return __builtin_bit_cast(unsigned, v);
}
__device__ __forceinline__ h2 shfl_xor_h2(h2 v, int m) {
  int i = __builtin_bit_cast(int, v);
  i = __shfl_xor(i, m, 64);
  return __builtin_bit_cast(h2, i);
}
__device__ __forceinline__ u16 f2h(float f) {
  _Float16 h = (_Float16)f;
  return __builtin_bit_cast(u16, h);
}
__device__ __forceinline__ unsigned scale_h2(unsigned u, float rinv) {
  h2 v = as_h2(u);
  h2 o;
  o.x = (_Float16)((float)v.x * rinv);
  o.y = (_Float16)((float)v.y * rinv);
  return as_u(o);
}

// ---------------------------------------------------------------------------
__global__ __launch_bounds__(256) void to_f16(
    const float* __restrict__ in, u16* __restrict__ outv, int n) {
  int i = blockIdx.x * 256 + threadIdx.x;
  if (i < n) outv[i] = f2h(in[i]);
}

// ---------------------------------------------------------------------------
// CSR build (R5 pipeline): per-WG count -> scans -> exact-offset place
// (zero global atomics) -> per-bucket fill (emits row_ptr for free).
// ---------------------------------------------------------------------------
__global__ __launch_bounds__(256) void csr_count(
    const int* __restrict__ dst, int* __restrict__ counts) {
  __shared__ int h[NB];
  int w = blockIdx.x, tid = threadIdx.x;
  for (int i = tid; i < NB; i += 256) h[i] = 0;
  __syncthreads();
  int e0 = w * CHUNK;
  for (int i = tid; i < CHUNK; i += 256)
    atomicAdd(&h[dst[e0 + i] >> BSHIFT], 1);
  __syncthreads();
  for (int i = tid; i < NB; i += 256) counts[w * NB + i] = h[i];
}

__global__ __launch_bounds__(256) void csr_scan_w(
    int* __restrict__ counts, int* __restrict__ btot) {
  __shared__ int s[256];
  int b = blockIdx.x, tid = threadIdx.x;
  int v = counts[tid * NB + b];
  s[tid] = v;
  __syncthreads();
  for (int off = 1; off < 256; off <<= 1) {
    int t = (tid >= off) ? s[tid - off] : 0;
    __syncthreads();
    s[tid] += t;
    __syncthreads();
  }
  counts[tid * NB + b] = s[tid] - v;
  if (tid == 255) btot[b] = s[255];
}

__global__ __launch_bounds__(256) void csr_scan_b(
    const int* __restrict__ btot, int* __restrict__ bbase) {
  __shared__ int s[256];
  int tid = threadIdx.x;
  int g0 = tid * 2, g1 = tid * 2 + 1;
  int v0 = (g0 < NB) ? btot[g0] : 0;
  int v1 = (g1 < NB) ? btot[g1] : 0;
  int tsum = v0 + v1;
  s[tid] = tsum;
  __syncthreads();
  for (int off = 1; off < 256; off <<= 1) {
    int t = (tid >= off) ? s[tid - off] : 0;
    __syncthreads();
    s[tid] += t;
    __syncthreads();
  }
  int run = s[tid] - tsum;
  if (g0 < NB) bbase[g0] = run;
  if (g1 < NB) bbase[g1] = run + v0;
  if (tid == 0) bbase[NB] = N_EDGES;
}

__global__ __launch_bounds__(256) void csr_place(
    const int* __restrict__ src, const int* __restrict__ dst,
    const int* __restrict__ counts, const int* __restrict__ bbase,
    unsigned* __restrict__ staged) {
  __shared__ int cur[NB];
  int w = blockIdx.x, tid = threadIdx.x;
  for (int i = tid; i < NB; i += 256) cur[i] = bbase[i] + counts[w * NB + i];
  __syncthreads();
  int e0 = w * CHUNK;
  for (int i = tid; i < CHUNK; i += 256) {
    int d = dst[e0 + i];
    int b = d >> BSHIFT;
    int pos = atomicAdd(&cur[b], 1);
    staged[pos] = ((unsigned)src[e0 + i] << 8) | (unsigned)(d & (BNODES - 1));
  }
}

__global__ __launch_bounds__(256) void csr_fill(
    const unsigned* __restrict__ staged, const int* __restrict__ bbase,
    int* __restrict__ row_ptr, int* __restrict__ sorted_src) {
  __shared__ int s_cnt[BNODES];
  __shared__ int s_scan[BNODES];
  int b = blockIdx.x, tid = threadIdx.x;
  int n0 = b << BSHIFT;
  int beg = bbase[b], end = bbase[b + 1];
  s_cnt[tid] = 0;
  __syncthreads();
  for (int i = beg + tid; i < end; i += 256)
    atomicAdd(&s_cnt[staged[i] & (BNODES - 1)], 1);
  __syncthreads();
  int v = s_cnt[tid];
  s_scan[tid] = v;
  __syncthreads();
  for (int off = 1; off < BNODES; off <<= 1) {
    int t = (tid >= off) ? s_scan[tid - off] : 0;
    __syncthreads();
    s_scan[tid] += t;
    __syncthreads();
  }
  int excl = s_scan[tid] - v;
  int node = n0 + tid;
  if (node < N_NODES) row_ptr[node] = beg + excl;
  if (b == 0 && tid == 0) row_ptr[N_NODES] = N_EDGES;
  s_cnt[tid] = excl;
  __syncthreads();
  for (int i = beg + tid; i < end; i += 256) {
    unsigned p = staged[i];
    int r = atomicAdd(&s_cnt[p & (BNODES - 1)], 1);
    sorted_src[beg + r] = (int)(p >> 8);
  }
}

// ---------------------------------------------------------------------------
// Layer 1: 16 nodes/block, 4 waves. Gather: 4 lanes/edge x 16B loads,
// 16 groups x 2-deep = 32 edges in flight/wave. MFMA epilogue:
// C[16x64] = feat[16x64].[w1l;w1r], +bias, relu -> h1h (f16).
// ---------------------------------------------------------------------------
#define F1 72   // feat stride (u16): 144B rows, 16B-aligned
#define WS1 40  // weight stride (u16): 80B rows, 2-way banks max
__global__ __launch_bounds__(256) void layer1_fused(
    const u16* __restrict__ xh, const int* __restrict__ row_ptr,
    const int* __restrict__ sorted_src, const float* __restrict__ w_l,
    const float* __restrict__ b_l, const float* __restrict__ w_r,
    u16* __restrict__ h1h) {
  __shared__ __align__(16) u16 s_wl[HID * WS1];
  __shared__ __align__(16) u16 s_wr[HID * WS1];
  __shared__ __align__(16) u16 s_feat[16 * F1];

  int tid = threadIdx.x;
  for (int idx = tid; idx < HID * IN_DIM; idx += 256) {
    int j = idx >> 5, f = idx & 31;
    s_wl[j * WS1 + f] = f2h(w_l[idx]);
    s_wr[j * WS1 + f] = f2h(w_r[idx]);
  }
  int w = tid >> 6, lane = tid & 63;
  int q = lane & 3, g = lane >> 2;  // 16 groups of 4; lane owns ch 8q..8q+7

  for (int m = 0; m < 4; ++m) {
    int nl = 4 * w + m;
    int node = blockIdx.x * 16 + nl;
    int rs = row_ptr[node];
    int deg = row_ptr[node + 1] - rs;
    h2 a0{}, a1{}, a2{}, a3{}, b0{}, b1{}, b2{}, b3{};
    int kk = g;
    for (; kk + 16 < deg; kk += 32) {
      int s0 = sorted_src[rs + kk];
      int s1 = sorted_src[rs + kk + 16];
      uint4 u0 = *(const uint4*)&xh[s0 * IN_DIM + 8 * q];
      uint4 u1 = *(const uint4*)&xh[s1 * IN_DIM + 8 * q];
      a0 += as_h2(u0.x); a1 += as_h2(u0.y); a2 += as_h2(u0.z); a3 += as_h2(u0.w);
      b0 += as_h2(u1.x); b1 += as_h2(u1.y); b2 += as_h2(u1.z); b3 += as_h2(u1.w);
    }
    if (kk < deg) {
      int s0 = sorted_src[rs + kk];
      uint4 u0 = *(const uint4*)&xh[s0 * IN_DIM + 8 * q];
      a0 += as_h2(u0.x); a1 += as_h2(u0.y); a2 += as_h2(u0.z); a3 += as_h2(u0.w);
    }
    a0 += b0; a1 += b1; a2 += b2; a3 += b3;
#pragma unroll
    for (int off = 4; off < 64; off <<= 1) {
      a0 += shfl_xor_h2(a0, off);
      a1 += shfl_xor_h2(a1, off);
      a2 += shfl_xor_h2(a2, off);
      a3 += shfl_xor_h2(a3, off);
    }
    if (g == 0) {
      float rinv = 1.0f / fmaxf((float)deg, 1.0f);
      uint4 o;
      o.x = scale_h2(as_u(a0), rinv);
      o.y = scale_h2(as_u(a1), rinv);
      o.z = scale_h2(as_u(a2), rinv);
      o.w = scale_h2(as_u(a3), rinv);
      *(uint4*)&s_feat[nl * F1 + 8 * q] = o;
    }
  }
  // root x copy: wave w covers its 4 nodes; 16 lanes x 2ch each
  {
    int nm = lane >> 4, q2 = lane & 15;
    int nl = 4 * w + nm;
    int node = blockIdx.x * 16 + nl;
    unsigned ux = *(const unsigned*)&xh[node * IN_DIM + 2 * q2];
    *(unsigned*)&s_feat[nl * F1 + IN_DIM + 2 * q2] = ux;
  }
  __syncthreads();

  // MFMA epilogue: wave w computes out cols 16w..16w+15 for all 16 nodes
  int q16 = lane & 15, g4 = lane >> 4;
  int j = 16 * w + q16;
  half8 a0f = *(const half8*)&s_feat[q16 * F1 + 8 * g4];
  half8 a1f = *(const half8*)&s_feat[q16 * F1 + 32 + 8 * g4];
  half8 b0f = *(const half8*)&s_wl[j * WS1 + 8 * g4];
  half8 b1f = *(const half8*)&s_wr[j * WS1 + 8 * g4];
  float4v acc = {};
  acc = __builtin_amdgcn_mfma_f32_16x16x32_f16(a0f, b0f, acc, 0, 0, 0);
  acc = __builtin_amdgcn_mfma_f32_16x16x32_f16(a1f, b1f, acc, 0, 0, 0);
  float bj = b_l[j];
#pragma unroll
  for (int reg = 0; reg < 4; ++reg) {
    int nl = 4 * g4 + reg;
    float v = fmaxf(acc[reg] + bj, 0.0f);
    h1h[(blockIdx.x * 16 + nl) * HID + j] = f2h(v);
  }
}

// ---------------------------------------------------------------------------
// Layer 2: 16 nodes/block, 4 waves. Gather: 8 lanes/edge x 16B loads,
// 8 groups x 2-deep = 16 edges in flight/wave. MFMA epilogue + classifier.
// ---------------------------------------------------------------------------
#define F2 136  // feat stride (u16): 272B rows, 16B-aligned
#define WS2 72  // weight stride (u16): 144B rows, 2-way banks max
__global__ __launch_bounds__(256) void layer2_fused(
    const u16* __restrict__ h1h, const int* __restrict__ row_ptr,
    const int* __restrict__ sorted_src, const float* __restrict__ w_l,
    const float* __restrict__ b_l, const float* __restrict__ w_r,
    const float* __restrict__ wc, const float* __restrict__ bc,
    float* __restrict__ out) {
  __shared__ __align__(16) u16 s_wl[HID * WS2];
  __shared__ __align__(16) u16 s_wr[HID * WS2];
  __shared__ __align__(16) u16 s_feat[16 * F2];
  __shared__ float s_wc[HID];
  __shared__ float s_out[16];

  int tid = threadIdx.x;
  for (int idx = tid; idx < HID * HID; idx += 256) {
    int j = idx >> 6, f = idx & 63;
    s_wl[j * WS2 + f] = f2h(w_l[idx]);
    s_wr[j * WS2 + f] = f2h(w_r[idx]);
  }
  if (tid < HID) s_wc[tid] = wc[tid];
  if (tid < 16) s_out[tid] = bc[0];

  int w = tid >> 6, lane = tid & 63;
  int q = lane & 7, g = lane >> 3;  // 8 groups of 8; lane owns ch 8q..8q+7

  for (int m = 0; m < 4; ++m) {
    int nl = 4 * w + m;
    int node = blockIdx.x * 16 + nl;
    int rs = row_ptr[node];
    int deg = row_ptr[node + 1] - rs;
    h2 a0{}, a1{}, a2{}, a3{}, b0{}, b1{}, b2{}, b3{};
    int kk = g;
    for (; kk + 8 < deg; kk += 16) {
      int s0 = sorted_src[rs + kk];
      int s1 = sorted_src[rs + kk + 8];
      uint4 u0 = *(const uint4*)&h1h[s0 * HID + 8 * q];
      uint4 u1 = *(const uint4*)&h1h[s1 * HID + 8 * q];
      a0 += as_h2(u0.x); a1 += as_h2(u0.y); a2 += as_h2(u0.z); a3 += as_h2(u0.w);
      b0 += as_h2(u1.x); b1 += as_h2(u1.y); b2 += as_h2(u1.z); b3 += as_h2(u1.w);
    }
    if (kk < deg) {
      int s0 = sorted_src[rs + kk];
      uint4 u0 = *(const uint4*)&h1h[s0 * HID + 8 * q];
      a0 += as_h2(u0.x); a1 += as_h2(u0.y); a2 += as_h2(u0.z); a3 += as_h2(u0.w);
    }
    a0 += b0; a1 += b1; a2 += b2; a3 += b3;
#pragma unroll
    for (int off = 8; off < 64; off <<= 1) {
      a0 += shfl_xor_h2(a0, off);
      a1 += shfl_xor_h2(a1, off);
      a2 += shfl_xor_h2(a2, off);
      a3 += shfl_xor_h2(a3, off);
    }
    if (g == 0) {
      float rinv = 1.0f / fmaxf((float)deg, 1.0f);
      uint4 o;
      o.x = scale_h2(as_u(a0), rinv);
      o.y = scale_h2(as_u(a1), rinv);
      o.z = scale_h2(as_u(a2), rinv);
      o.w = scale_h2(as_u(a3), rinv);
      *(uint4*)&s_feat[nl * F2 + 8 * q] = o;
    }
  }
  // root h1 copy: wave w covers its 4 nodes; 16 lanes x 4ch each
  {
    int nm = lane >> 4, q2 = lane & 15;
    int nl = 4 * w + nm;
    int node = blockIdx.x * 16 + nl;
    uint2 uh = *(const uint2*)&h1h[node * HID + 4 * q2];
    *(uint2*)&s_feat[nl * F2 + HID + 4 * q2] = uh;
  }
  __syncthreads();

  // MFMA epilogue
  int q16 = lane & 15, g4 = lane >> 4;
  int j = 16 * w + q16;
  float4v acc = {};
#pragma unroll
  for (int t = 0; t < 4; ++t) {
    half8 af = *(const half8*)&s_feat[q16 * F2 + 32 * t + 8 * g4];
    half8 bf;
    if (t < 2)
      bf = *(const half8*)&s_wl[j * WS2 + 32 * t + 8 * g4];
    else
      bf = *(const half8*)&s_wr[j * WS2 + 32 * (t - 2) + 8 * g4];
    acc = __builtin_amdgcn_mfma_f32_16x16x32_f16(af, bf, acc, 0, 0, 0);
  }
  float bj = b_l[j];
  float wcj = s_wc[j];
#pragma unroll
  for (int reg = 0; reg < 4; ++reg) {
    float v = fmaxf(acc[reg] + bj, 0.0f) * wcj;
    v += __shfl_xor(v, 1, 64);
    v += __shfl_xor(v, 2, 64);
    v += __shfl_xor(v, 4, 64);
    v += __shfl_xor(v, 8, 64);
    if (q16 == 0) atomicAdd(&s_out[4 * g4 + reg], v);
  }
  __syncthreads();
  if (tid < 16) out[blockIdx.x * 16 + tid] = s_out[tid];
}

// ---------------------------------------------------------------------------
extern "C" void kernel_launch(void* const* d_in, const int* in_sizes, int n_in,
                              void* d_out, int out_size, void* d_ws, size_t ws_size,
                              hipStream_t stream) {
  const float* x   = (const float*)d_in[0];
  const int*   ei  = (const int*)d_in[1];
  const float* w1l = (const float*)d_in[2];
  const float* b1l = (const float*)d_in[3];
  const float* w1r = (const float*)d_in[4];
  const float* w2l = (const float*)d_in[5];
  const float* b2l = (const float*)d_in[6];
  const float* w2r = (const float*)d_in[7];
  const float* wc  = (const float*)d_in[8];
  const float* bc  = (const float*)d_in[9];
  float* out = (float*)d_out;

  const int* src = ei;             // edge_index[0]
  const int* dst = ei + N_EDGES;   // edge_index[1]

  // workspace layout
  char* ws = (char*)d_ws;
  int*      row_ptr    = (int*)(ws + 0);          // 400,004 B
  int*      counts     = (int*)(ws + 400128);     // NWG*NB*4 = 400,384 B
  int*      btot       = (int*)(ws + 800768);     // 1,564 B
  int*      bbase      = (int*)(ws + 802560);     // 1,568 B
  unsigned* staged     = (unsigned*)(ws + 804352);// E*4 = 12.8 MB
  int*      sorted_src = (int*)(ws + 13604352);   // E*4 = 12.8 MB
  u16*      xh         = (u16*)(ws + 26404352);   // 6.4 MB
  u16*      h1h        = (u16*)(ws + 32804352);   // 12.8 MB
  // total 45,604,352 B

  to_f16<<<(N_NODES * IN_DIM + 255) / 256, 256, 0, stream>>>(x, xh,
                                                             N_NODES * IN_DIM);
  csr_count<<<NWG, 256, 0, stream>>>(dst, counts);
  csr_scan_w<<<NB, 256, 0, stream>>>(counts, btot);
  csr_scan_b<<<1, 256, 0, stream>>>(btot, bbase);
  csr_place<<<NWG, 256, 0, stream>>>(src, dst, counts, bbase, staged);
  csr_fill<<<NB, 256, 0, stream>>>(staged, bbase, row_ptr, sorted_src);
  layer1_fused<<<N_NODES / 16, 256, 0, stream>>>(xh, row_ptr, sorted_src,
                                                 w1l, b1l, w1r, h1h);
  layer2_fused<<<N_NODES / 16, 256, 0, stream>>>(h1h, row_ptr, sorted_src,
                                                 w2l, b2l, w2r, wc, bc, out);
}

// Round 8
// 198.970 us; speedup vs baseline: 3.8026x; 1.0536x over previous
//
#include <hip/hip_runtime.h>

#define N_NODES 100000
#define N_EDGES 3200000
#define IN_DIM 32
#define HID 64
#define BSHIFT 8
#define BNODES 256                              // nodes per bucket
#define NB ((N_NODES + BNODES - 1) / BNODES)    // 391 buckets
#define NWG 256                                 // WGs for count/place
#define CHUNK (N_EDGES / NWG)                   // 12500 edges per WG (exact)

typedef unsigned short u16;
typedef _Float16 h2 __attribute__((ext_vector_type(2)));
typedef _Float16 half8 __attribute__((ext_vector_type(8)));
typedef float float4v __attribute__((ext_vector_type(4)));

__device__ __forceinline__ h2 as_h2(unsigned u) {
  return __builtin_bit_cast(h2, u);
}
__device__ __forceinline__ unsigned as_u(h2 v) {
  return __builtin_bit_cast(unsigned, v);
}
__device__ __forceinline__ h2 shfl_xor_h2(h2 v, int m) {
  int i = __builtin_bit_cast(int, v);
  i = __shfl_xor(i, m, 64);
  return __builtin_bit_cast(h2, i);
}
__device__ __forceinline__ u16 f2h(float f) {
  _Float16 h = (_Float16)f;
  return __builtin_bit_cast(u16, h);
}
__device__ __forceinline__ unsigned scale_h2(unsigned u, float rinv) {
  h2 v = as_h2(u);
  h2 o;
  o.x = (_Float16)((float)v.x * rinv);
  o.y = (_Float16)((float)v.y * rinv);
  return as_u(o);
}

// ---------------------------------------------------------------------------
__global__ __launch_bounds__(256) void to_f16(
    const float* __restrict__ in, u16* __restrict__ outv, int n) {
  int i = blockIdx.x * 256 + threadIdx.x;
  if (i < n) outv[i] = f2h(in[i]);
}

// One-shot weight conversion: f32 -> f16 for all four weight matrices.
__global__ __launch_bounds__(256) void prep_weights(
    const float* __restrict__ w1l, const float* __restrict__ w1r,
    const float* __restrict__ w2l, const float* __restrict__ w2r,
    u16* __restrict__ w1lf, u16* __restrict__ w1rf,
    u16* __restrict__ w2lf, u16* __restrict__ w2rf) {
  int i = blockIdx.x * 256 + threadIdx.x;
  if (i < HID * IN_DIM) {
    w1lf[i] = f2h(w1l[i]);
    w1rf[i] = f2h(w1r[i]);
  }
  if (i < HID * HID) {
    w2lf[i] = f2h(w2l[i]);
    w2rf[i] = f2h(w2r[i]);
  }
}

// ---------------------------------------------------------------------------
// CSR build (R5 pipeline): per-WG count -> scans -> exact-offset place
// (zero global atomics) -> per-bucket fill (emits row_ptr for free).
// ---------------------------------------------------------------------------
__global__ __launch_bounds__(256) void csr_count(
    const int* __restrict__ dst, int* __restrict__ counts) {
  __shared__ int h[NB];
  int w = blockIdx.x, tid = threadIdx.x;
  for (int i = tid; i < NB; i += 256) h[i] = 0;
  __syncthreads();
  int e0 = w * CHUNK;
  for (int i = tid; i < CHUNK; i += 256)
    atomicAdd(&h[dst[e0 + i] >> BSHIFT], 1);
  __syncthreads();
  for (int i = tid; i < NB; i += 256) counts[w * NB + i] = h[i];
}

__global__ __launch_bounds__(256) void csr_scan_w(
    int* __restrict__ counts, int* __restrict__ btot) {
  __shared__ int s[256];
  int b = blockIdx.x, tid = threadIdx.x;
  int v = counts[tid * NB + b];
  s[tid] = v;
  __syncthreads();
  for (int off = 1; off < 256; off <<= 1) {
    int t = (tid >= off) ? s[tid - off] : 0;
    __syncthreads();
    s[tid] += t;
    __syncthreads();
  }
  counts[tid * NB + b] = s[tid] - v;
  if (tid == 255) btot[b] = s[255];
}

__global__ __launch_bounds__(256) void csr_scan_b(
    const int* __restrict__ btot, int* __restrict__ bbase) {
  __shared__ int s[256];
  int tid = threadIdx.x;
  int g0 = tid * 2, g1 = tid * 2 + 1;
  int v0 = (g0 < NB) ? btot[g0] : 0;
  int v1 = (g1 < NB) ? btot[g1] : 0;
  int tsum = v0 + v1;
  s[tid] = tsum;
  __syncthreads();
  for (int off = 1; off < 256; off <<= 1) {
    int t = (tid >= off) ? s[tid - off] : 0;
    __syncthreads();
    s[tid] += t;
    __syncthreads();
  }
  int run = s[tid] - tsum;
  if (g0 < NB) bbase[g0] = run;
  if (g1 < NB) bbase[g1] = run + v0;
  if (tid == 0) bbase[NB] = N_EDGES;
}

__global__ __launch_bounds__(256) void csr_place(
    const int* __restrict__ src, const int* __restrict__ dst,
    const int* __restrict__ counts, const int* __restrict__ bbase,
    unsigned* __restrict__ staged) {
  __shared__ int cur[NB];
  int w = blockIdx.x, tid = threadIdx.x;
  for (int i = tid; i < NB; i += 256) cur[i] = bbase[i] + counts[w * NB + i];
  __syncthreads();
  int e0 = w * CHUNK;
  for (int i = tid; i < CHUNK; i += 256) {
    int d = dst[e0 + i];
    int b = d >> BSHIFT;
    int pos = atomicAdd(&cur[b], 1);
    staged[pos] = ((unsigned)src[e0 + i] << 8) | (unsigned)(d & (BNODES - 1));
  }
}

__global__ __launch_bounds__(256) void csr_fill(
    const unsigned* __restrict__ staged, const int* __restrict__ bbase,
    int* __restrict__ row_ptr, int* __restrict__ sorted_src) {
  __shared__ int s_cnt[BNODES];
  __shared__ int s_scan[BNODES];
  int b = blockIdx.x, tid = threadIdx.x;
  int n0 = b << BSHIFT;
  int beg = bbase[b], end = bbase[b + 1];
  s_cnt[tid] = 0;
  __syncthreads();
  for (int i = beg + tid; i < end; i += 256)
    atomicAdd(&s_cnt[staged[i] & (BNODES - 1)], 1);
  __syncthreads();
  int v = s_cnt[tid];
  s_scan[tid] = v;
  __syncthreads();
  for (int off = 1; off < BNODES; off <<= 1) {
    int t = (tid >= off) ? s_scan[tid - off] : 0;
    __syncthreads();
    s_scan[tid] += t;
    __syncthreads();
  }
  int excl = s_scan[tid] - v;
  int node = n0 + tid;
  if (node < N_NODES) row_ptr[node] = beg + excl;
  if (b == 0 && tid == 0) row_ptr[N_NODES] = N_EDGES;
  s_cnt[tid] = excl;
  __syncthreads();
  for (int i = beg + tid; i < end; i += 256) {
    unsigned p = staged[i];
    int r = atomicAdd(&s_cnt[p & (BNODES - 1)], 1);
    sorted_src[beg + r] = (int)(p >> 8);
  }
}

// ---------------------------------------------------------------------------
// Layer 1: 16 nodes/block, 4 waves. Gather: 4 lanes/edge x 16B loads,
// 16 groups x 2-deep = 32 edges in flight/wave. MFMA epilogue with
// register B-fragments (f16 weights straight from global; no weight LDS).
// ---------------------------------------------------------------------------
#define F1 72   // feat stride (u16): 144B rows, 16B-aligned
__global__ __launch_bounds__(256) void layer1_fused(
    const u16* __restrict__ xh, const int* __restrict__ row_ptr,
    const int* __restrict__ sorted_src, const u16* __restrict__ w_lf,
    const float* __restrict__ b_l, const u16* __restrict__ w_rf,
    u16* __restrict__ h1h) {
  __shared__ __align__(16) u16 s_feat[16 * F1];

  int tid = threadIdx.x;
  int w = tid >> 6, lane = tid & 63;
  int q = lane & 3, g = lane >> 2;  // 16 groups of 4; lane owns ch 8q..8q+7

  for (int m = 0; m < 4; ++m) {
    int nl = 4 * w + m;
    int node = blockIdx.x * 16 + nl;
    int rs = row_ptr[node];
    int deg = row_ptr[node + 1] - rs;
    h2 a0{}, a1{}, a2{}, a3{}, b0{}, b1{}, b2{}, b3{};
    int kk = g;
    for (; kk + 16 < deg; kk += 32) {
      int s0 = sorted_src[rs + kk];
      int s1 = sorted_src[rs + kk + 16];
      uint4 u0 = *(const uint4*)&xh[s0 * IN_DIM + 8 * q];
      uint4 u1 = *(const uint4*)&xh[s1 * IN_DIM + 8 * q];
      a0 += as_h2(u0.x); a1 += as_h2(u0.y); a2 += as_h2(u0.z); a3 += as_h2(u0.w);
      b0 += as_h2(u1.x); b1 += as_h2(u1.y); b2 += as_h2(u1.z); b3 += as_h2(u1.w);
    }
    if (kk < deg) {
      int s0 = sorted_src[rs + kk];
      uint4 u0 = *(const uint4*)&xh[s0 * IN_DIM + 8 * q];
      a0 += as_h2(u0.x); a1 += as_h2(u0.y); a2 += as_h2(u0.z); a3 += as_h2(u0.w);
    }
    a0 += b0; a1 += b1; a2 += b2; a3 += b3;
#pragma unroll
    for (int off = 4; off < 64; off <<= 1) {
      a0 += shfl_xor_h2(a0, off);
      a1 += shfl_xor_h2(a1, off);
      a2 += shfl_xor_h2(a2, off);
      a3 += shfl_xor_h2(a3, off);
    }
    if (g == 0) {
      float rinv = 1.0f / fmaxf((float)deg, 1.0f);
      uint4 o;
      o.x = scale_h2(as_u(a0), rinv);
      o.y = scale_h2(as_u(a1), rinv);
      o.z = scale_h2(as_u(a2), rinv);
      o.w = scale_h2(as_u(a3), rinv);
      *(uint4*)&s_feat[nl * F1 + 8 * q] = o;
    }
  }
  // root x copy: wave w covers its 4 nodes; 16 lanes x 2ch each
  {
    int nm = lane >> 4, q2 = lane & 15;
    int nl = 4 * w + nm;
    int node = blockIdx.x * 16 + nl;
    unsigned ux = *(const unsigned*)&xh[node * IN_DIM + 2 * q2];
    *(unsigned*)&s_feat[nl * F1 + IN_DIM + 2 * q2] = ux;
  }
  __syncthreads();

  // MFMA epilogue: wave w computes out cols 16w..16w+15 for all 16 nodes
  int q16 = lane & 15, g4 = lane >> 4;
  int j = 16 * w + q16;
  half8 b0f = *(const half8*)&w_lf[j * IN_DIM + 8 * g4];
  half8 b1f = *(const half8*)&w_rf[j * IN_DIM + 8 * g4];
  half8 a0f = *(const half8*)&s_feat[q16 * F1 + 8 * g4];
  half8 a1f = *(const half8*)&s_feat[q16 * F1 + 32 + 8 * g4];
  float4v acc = {};
  acc = __builtin_amdgcn_mfma_f32_16x16x32_f16(a0f, b0f, acc, 0, 0, 0);
  acc = __builtin_amdgcn_mfma_f32_16x16x32_f16(a1f, b1f, acc, 0, 0, 0);
  float bj = b_l[j];
#pragma unroll
  for (int reg = 0; reg < 4; ++reg) {
    int nl = 4 * g4 + reg;
    float v = fmaxf(acc[reg] + bj, 0.0f);
    h1h[(blockIdx.x * 16 + nl) * HID + j] = f2h(v);
  }
}

// ---------------------------------------------------------------------------
// Layer 2: 16 nodes/block, 4 waves. Gather: 8 lanes/edge x 16B loads,
// 8 groups x 2-deep = 16 edges in flight/wave. MFMA epilogue with register
// B-fragments + fused classifier.
// ---------------------------------------------------------------------------
#define F2 136  // feat stride (u16): 272B rows, 16B-aligned
__global__ __launch_bounds__(256) void layer2_fused(
    const u16* __restrict__ h1h, const int* __restrict__ row_ptr,
    const int* __restrict__ sorted_src, const u16* __restrict__ w_lf,
    const float* __restrict__ b_l, const u16* __restrict__ w_rf,
    const float* __restrict__ wc, const float* __restrict__ bc,
    float* __restrict__ out) {
  __shared__ __align__(16) u16 s_feat[16 * F2];
  __shared__ float s_out[16];

  int tid = threadIdx.x;
  if (tid < 16) s_out[tid] = bc[0];

  int w = tid >> 6, lane = tid & 63;
  int q = lane & 7, g = lane >> 3;  // 8 groups of 8; lane owns ch 8q..8q+7

  for (int m = 0; m < 4; ++m) {
    int nl = 4 * w + m;
    int node = blockIdx.x * 16 + nl;
    int rs = row_ptr[node];
    int deg = row_ptr[node + 1] - rs;
    h2 a0{}, a1{}, a2{}, a3{}, b0{}, b1{}, b2{}, b3{};
    int kk = g;
    for (; kk + 8 < deg; kk += 16) {
      int s0 = sorted_src[rs + kk];
      int s1 = sorted_src[rs + kk + 8];
      uint4 u0 = *(const uint4*)&h1h[s0 * HID + 8 * q];
      uint4 u1 = *(const uint4*)&h1h[s1 * HID + 8 * q];
      a0 += as_h2(u0.x); a1 += as_h2(u0.y); a2 += as_h2(u0.z); a3 += as_h2(u0.w);
      b0 += as_h2(u1.x); b1 += as_h2(u1.y); b2 += as_h2(u1.z); b3 += as_h2(u1.w);
    }
    if (kk < deg) {
      int s0 = sorted_src[rs + kk];
      uint4 u0 = *(const uint4*)&h1h[s0 * HID + 8 * q];
      a0 += as_h2(u0.x); a1 += as_h2(u0.y); a2 += as_h2(u0.z); a3 += as_h2(u0.w);
    }
    a0 += b0; a1 += b1; a2 += b2; a3 += b3;
#pragma unroll
    for (int off = 8; off < 64; off <<= 1) {
      a0 += shfl_xor_h2(a0, off);
      a1 += shfl_xor_h2(a1, off);
      a2 += shfl_xor_h2(a2, off);
      a3 += shfl_xor_h2(a3, off);
    }
    if (g == 0) {
      float rinv = 1.0f / fmaxf((float)deg, 1.0f);
      uint4 o;
      o.x = scale_h2(as_u(a0), rinv);
      o.y = scale_h2(as_u(a1), rinv);
      o.z = scale_h2(as_u(a2), rinv);
      o.w = scale_h2(as_u(a3), rinv);
      *(uint4*)&s_feat[nl * F2 + 8 * q] = o;
    }
  }
  // root h1 copy: wave w covers its 4 nodes; 16 lanes x 4ch each
  {
    int nm = lane >> 4, q2 = lane & 15;
    int nl = 4 * w + nm;
    int node = blockIdx.x * 16 + nl;
    uint2 uh = *(const uint2*)&h1h[node * HID + 4 * q2];
    *(uint2*)&s_feat[nl * F2 + HID + 4 * q2] = uh;
  }
  __syncthreads();

  // MFMA epilogue: register B-fragments from global f16 weights (L2-hot)
  int q16 = lane & 15, g4 = lane >> 4;
  int j = 16 * w + q16;
  half8 bf0 = *(const half8*)&w_lf[j * HID + 8 * g4];
  half8 bf1 = *(const half8*)&w_lf[j * HID + 32 + 8 * g4];
  half8 bf2 = *(const half8*)&w_rf[j * HID + 8 * g4];
  half8 bf3 = *(const half8*)&w_rf[j * HID + 32 + 8 * g4];
  float4v acc = {};
  acc = __builtin_amdgcn_mfma_f32_16x16x32_f16(
      *(const half8*)&s_feat[q16 * F2 + 8 * g4], bf0, acc, 0, 0, 0);
  acc = __builtin_amdgcn_mfma_f32_16x16x32_f16(
      *(const half8*)&s_feat[q16 * F2 + 32 + 8 * g4], bf1, acc, 0, 0, 0);
  acc = __builtin_amdgcn_mfma_f32_16x16x32_f16(
      *(const half8*)&s_feat[q16 * F2 + 64 + 8 * g4], bf2, acc, 0, 0, 0);
  acc = __builtin_amdgcn_mfma_f32_16x16x32_f16(
      *(const half8*)&s_feat[q16 * F2 + 96 + 8 * g4], bf3, acc, 0, 0, 0);
  float bj = b_l[j];
  float wcj = wc[j];
#pragma unroll
  for (int reg = 0; reg < 4; ++reg) {
    float v = fmaxf(acc[reg] + bj, 0.0f) * wcj;
    v += __shfl_xor(v, 1, 64);
    v += __shfl_xor(v, 2, 64);
    v += __shfl_xor(v, 4, 64);
    v += __shfl_xor(v, 8, 64);
    if (q16 == 0) atomicAdd(&s_out[4 * g4 + reg], v);
  }
  __syncthreads();
  if (tid < 16) out[blockIdx.x * 16 + tid] = s_out[tid];
}

// ---------------------------------------------------------------------------
extern "C" void kernel_launch(void* const* d_in, const int* in_sizes, int n_in,
                              void* d_out, int out_size, void* d_ws, size_t ws_size,
                              hipStream_t stream) {
  const float* x   = (const float*)d_in[0];
  const int*   ei  = (const int*)d_in[1];
  const float* w1l = (const float*)d_in[2];
  const float* b1l = (const float*)d_in[3];
  const float* w1r = (const float*)d_in[4];
  const float* w2l = (const float*)d_in[5];
  const float* b2l = (const float*)d_in[6];
  const float* w2r = (const float*)d_in[7];
  const float* wc  = (const float*)d_in[8];
  const float* bc  = (const float*)d_in[9];
  float* out = (float*)d_out;

  const int* src = ei;             // edge_index[0]
  const int* dst = ei + N_EDGES;   // edge_index[1]

  // workspace layout
  char* ws = (char*)d_ws;
  int*      row_ptr    = (int*)(ws + 0);          // 400,004 B
  int*      counts     = (int*)(ws + 400128);     // NWG*NB*4 = 400,384 B
  int*      btot       = (int*)(ws + 800768);     // 1,564 B
  int*      bbase      = (int*)(ws + 802560);     // 1,568 B
  unsigned* staged     = (unsigned*)(ws + 804352);// E*4 = 12.8 MB
  int*      sorted_src = (int*)(ws + 13604352);   // E*4 = 12.8 MB
  u16*      xh         = (u16*)(ws + 26404352);   // 6.4 MB
  u16*      h1h        = (u16*)(ws + 32804352);   // 12.8 MB
  u16*      w1lf       = (u16*)(ws + 45604352);   // 4 KB
  u16*      w1rf       = (u16*)(ws + 45608448);   // 4 KB
  u16*      w2lf       = (u16*)(ws + 45612544);   // 8 KB
  u16*      w2rf       = (u16*)(ws + 45620736);   // 8 KB
  // total 45,628,928 B

  to_f16<<<(N_NODES * IN_DIM + 255) / 256, 256, 0, stream>>>(x, xh,
                                                             N_NODES * IN_DIM);
  prep_weights<<<(HID * HID + 255) / 256, 256, 0, stream>>>(
      w1l, w1r, w2l, w2r, w1lf, w1rf, w2lf, w2rf);
  csr_count<<<NWG, 256, 0, stream>>>(dst, counts);
  csr_scan_w<<<NB, 256, 0, stream>>>(counts, btot);
  csr_scan_b<<<1, 256, 0, stream>>>(btot, bbase);
  csr_place<<<NWG, 256, 0, stream>>>(src, dst, counts, bbase, staged);
  csr_fill<<<NB, 256, 0, stream>>>(staged, bbase, row_ptr, sorted_src);
  layer1_fused<<<N_NODES / 16, 256, 0, stream>>>(xh, row_ptr, sorted_src,
                                                 w1lf, b1l, w1rf, h1h);
  layer2_fused<<<N_NODES / 16, 256, 0, stream>>>(h1h, row_ptr, sorted_src,
                                                 w2lf, b2l, w2rf, wc, bc, out);
}